// Round 3
// baseline (1165.197 us; speedup 1.0000x reference)
//
#include <hip/hip_runtime.h>

// VQ-VAE vector quantizer forward (fp32).
// inputs: (32,256,32,32) f32 -> flat rows N=32768 x D=256
// embedding: (D=256, K=1024) f32, cluster_size: (1024,) f32
// outputs (flat f32): quantized[N*D], vq_loss, perplexity, code_usage, indices[N] (as float)

constexpr int DIM = 256;   // embedding dim (rows of embedding)
constexpr int NK  = 1024;  // number of codes (cols of embedding)
constexpr int RR  = 16;    // input rows per block in argmin kernel

// ---------------------------------------------------------------- enorm (0.5*|e_k|^2)
__global__ __launch_bounds__(256) void enorm_kernel(
    const float* __restrict__ emb, float* __restrict__ enorm) {
  int k = blockIdx.x * 256 + threadIdx.x;
  float s = 0.f;
  for (int d = 0; d < DIM; ++d) {
    float e = emb[(size_t)d * NK + k];   // coalesced across threads per d
    s = fmaf(e, e, s);
  }
  enorm[k] = 0.5f * s;                   // halved: argmin(|e|^2-2x.e) == argmin(0.5|e|^2-x.e)
}

// ---------------------------------------------------------------- argmin
// Block: 256 threads, RR=16 input rows vs all 1024 codes.
// Thread t owns codes 4t..4t+3 (float4-coalesced embedding loads).
// Double-buffered e-prefetch: each global load batch has a full 256-FMA
// block between issue and consumption. No token pasting (1.z lexes as a
// pp-number) — buffer vars passed by name.
#define LOADE(E0, E1, E2, E3, D4)                                           \
  E0 = *(const float4*)(emb + (size_t)((D4) * 4 + 0) * NK + k0);            \
  E1 = *(const float4*)(emb + (size_t)((D4) * 4 + 1) * NK + k0);            \
  E2 = *(const float4*)(emb + (size_t)((D4) * 4 + 2) * NK + k0);            \
  E3 = *(const float4*)(emb + (size_t)((D4) * 4 + 3) * NK + k0);

#define COMP(E0, E1, E2, E3, D4)                                                                 \
  _Pragma("unroll")                                                                              \
  for (int r = 0; r < RR; ++r) {                                                                 \
    const float4 xv = xs[r * (DIM / 4) + (D4)];                                                  \
    acc[r][0] = fmaf(xv.x, E0.x, fmaf(xv.y, E1.x, fmaf(xv.z, E2.x, fmaf(xv.w, E3.x, acc[r][0])))); \
    acc[r][1] = fmaf(xv.x, E0.y, fmaf(xv.y, E1.y, fmaf(xv.z, E2.y, fmaf(xv.w, E3.y, acc[r][1])))); \
    acc[r][2] = fmaf(xv.x, E0.z, fmaf(xv.y, E1.z, fmaf(xv.z, E2.z, fmaf(xv.w, E3.z, acc[r][2])))); \
    acc[r][3] = fmaf(xv.x, E0.w, fmaf(xv.y, E1.w, fmaf(xv.z, E2.w, fmaf(xv.w, E3.w, acc[r][3])))); \
  }

__global__ __launch_bounds__(256, 4) void argmin_kernel(
    const float* __restrict__ x, const float* __restrict__ emb,
    const float* __restrict__ enorm, int* __restrict__ idx_out,
    float* __restrict__ idx_out_f) {
  __shared__ float4 xs[RR * DIM / 4];    // 16 KB x-tile
  __shared__ float red_v[4][RR];
  __shared__ int   red_i[4][RR];

  const int tid = threadIdx.x;
  const size_t base = (size_t)blockIdx.x * (RR * DIM);

  {
    const float4* src = (const float4*)(x + base);
    #pragma unroll
    for (int i = 0; i < 4; ++i) xs[tid + 256 * i] = src[tid + 256 * i];
  }
  __syncthreads();

  float acc[RR][4];
  #pragma unroll
  for (int r = 0; r < RR; ++r) {
    #pragma unroll
    for (int j = 0; j < 4; ++j) acc[r][j] = 0.f;
  }

  const int k0 = tid * 4;
  float4 a0, a1, a2, a3, b0, b1, b2, b3;

  LOADE(a0, a1, a2, a3, 0)
  for (int d4 = 0; d4 < (DIM / 4) - 2; d4 += 2) {
    LOADE(b0, b1, b2, b3, d4 + 1)       // issue next-odd loads
    COMP(a0, a1, a2, a3, d4)            // 256 FMAs hide them
    LOADE(a0, a1, a2, a3, d4 + 2)       // issue next-even loads
    COMP(b0, b1, b2, b3, d4 + 1)
  }
  LOADE(b0, b1, b2, b3, (DIM / 4) - 1)
  COMP(a0, a1, a2, a3, (DIM / 4) - 2)
  COMP(b0, b1, b2, b3, (DIM / 4) - 1)

  const float4 en = *(const float4*)(enorm + k0);   // 0.5*|e|^2
  const int lane = tid & 63;
  const int wv   = tid >> 6;

  for (int r = 0; r < RR; ++r) {
    // score = 0.5|e|^2 - x.e  (row-constant |x|^2 and global 2x dropped; argmin unchanged)
    float bv = en.x - acc[r][0];
    int   bi = k0;
    { float v = en.y - acc[r][1]; if (v < bv) { bv = v; bi = k0 + 1; } }
    { float v = en.z - acc[r][2]; if (v < bv) { bv = v; bi = k0 + 2; } }
    { float v = en.w - acc[r][3]; if (v < bv) { bv = v; bi = k0 + 3; } }
    // 64-lane (val,idx) min-reduce, lowest index wins ties
    for (int off = 32; off > 0; off >>= 1) {
      float ov = __shfl_xor(bv, off);
      int   oi = __shfl_xor(bi, off);
      if (ov < bv || (ov == bv && oi < bi)) { bv = ov; bi = oi; }
    }
    if (lane == 0) { red_v[wv][r] = bv; red_i[wv][r] = bi; }
  }
  __syncthreads();

  if (tid < RR) {
    float bv = red_v[0][tid];
    int   bi = red_i[0][tid];
    #pragma unroll
    for (int w = 1; w < 4; ++w) {
      float v = red_v[w][tid]; int i2 = red_i[w][tid];
      if (v < bv || (v == bv && i2 < bi)) { bv = v; bi = i2; }
    }
    const int n = blockIdx.x * RR + tid;
    idx_out[n]   = bi;
    idx_out_f[n] = (float)bi;
  }
}

// ---------------------------------------------------------------- gather + loss partials
// Block: 256 threads x 8 elems = 2048 elems (8 rows).
__global__ __launch_bounds__(256) void gather_loss_kernel(
    const float* __restrict__ x, const float* __restrict__ emb,
    const int* __restrict__ idx, float* __restrict__ out_q,
    float* __restrict__ partial) {
  const int tid = threadIdx.x;
  const size_t base = (size_t)blockIdx.x * 2048;
  float local = 0.f;
  #pragma unroll
  for (int h = 0; h < 2; ++h) {
    const size_t g = base + (size_t)h * 1024 + (size_t)tid * 4;
    const int n = (int)(g >> 8);
    const int d = (int)(g & 255);
    const int k = idx[n];
    const float* ep = emb + (size_t)d * NK + k;
    float4 q;
    q.x = ep[0]; q.y = ep[NK]; q.z = ep[2 * NK]; q.w = ep[3 * NK];
    const float4 xv = *(const float4*)(x + g);
    *(float4*)(out_q + g) = q;
    const float dx = q.x - xv.x, dy = q.y - xv.y, dz = q.z - xv.z, dw = q.w - xv.w;
    local = fmaf(dx, dx, local);
    local = fmaf(dy, dy, local);
    local = fmaf(dz, dz, local);
    local = fmaf(dw, dw, local);
  }
  for (int off = 32; off > 0; off >>= 1) local += __shfl_down(local, off);
  __shared__ float wsum[4];
  if ((tid & 63) == 0) wsum[tid >> 6] = local;
  __syncthreads();
  if (tid == 0) partial[blockIdx.x] = (wsum[0] + wsum[1]) + (wsum[2] + wsum[3]);
}

// ---------------------------------------------------------------- finalize scalars
__global__ __launch_bounds__(1024) void finalize_kernel(
    const float* __restrict__ partial, int np,
    const float* __restrict__ cs, float* __restrict__ out_s,
    float inv_count) {
  __shared__ float sd[1024];
  const int tid = threadIdx.x;

  // 1) total squared diff
  float s = 0.f;
  for (int i = tid; i < np; i += 1024) s += partial[i];
  sd[tid] = s; __syncthreads();
  for (int st = 512; st > 0; st >>= 1) {
    if (tid < st) sd[tid] += sd[tid + st];
    __syncthreads();
  }
  const float total_sq = sd[0];
  __syncthreads();

  // 2) cluster_size sum
  const float c = cs[tid];
  sd[tid] = c; __syncthreads();
  for (int st = 512; st > 0; st >>= 1) {
    if (tid < st) sd[tid] += sd[tid + st];
    __syncthreads();
  }
  const float S = sd[0];
  __syncthreads();

  // 3) entropy term
  const float p = c / (S + 1e-5f);
  sd[tid] = p * logf(p + 1e-5f);
  __syncthreads();
  for (int st = 512; st > 0; st >>= 1) {
    if (tid < st) sd[tid] += sd[tid + st];
    __syncthreads();
  }
  const float T = sd[0];
  __syncthreads();

  // 4) used codes
  sd[tid] = (c > 1e-5f) ? 1.f : 0.f;
  __syncthreads();
  for (int st = 512; st > 0; st >>= 1) {
    if (tid < st) sd[tid] += sd[tid + st];
    __syncthreads();
  }
  const float U = sd[0];

  if (tid == 0) {
    out_s[0] = 1.25f * total_sq * inv_count;  // e_latent + 0.25*q_latent (equal in value)
    out_s[1] = expf(-T);                      // perplexity
    out_s[2] = U * (1.f / 1024.f);            // code usage rate
  }
}

// ---------------------------------------------------------------- launch
extern "C" void kernel_launch(void* const* d_in, const int* in_sizes, int n_in,
                              void* d_out, int out_size, void* d_ws, size_t ws_size,
                              hipStream_t stream) {
  const float* x   = (const float*)d_in[0];
  const float* emb = (const float*)d_in[1];
  const float* cs  = (const float*)d_in[2];
  float* out = (float*)d_out;

  const int N = in_sizes[0] / DIM;          // 32768
  const size_t ND = (size_t)N * DIM;        // 8388608

  // workspace layout
  float* enorm   = (float*)d_ws;                                           // 4 KB
  int*   idxw    = (int*)((char*)d_ws + NK * sizeof(float));               // 128 KB
  float* partial = (float*)((char*)d_ws + NK * sizeof(float) + (size_t)N * sizeof(int)); // 16 KB

  const int nGather = (int)(ND / 2048);     // 4096

  enorm_kernel<<<NK / 256, 256, 0, stream>>>(emb, enorm);
  argmin_kernel<<<N / RR, 256, 0, stream>>>(x, emb, enorm, idxw, out + ND + 3);
  gather_loss_kernel<<<nGather, 256, 0, stream>>>(x, emb, idxw, out, partial);
  finalize_kernel<<<1, 1024, 0, stream>>>(partial, nGather, cs, out + ND,
                                          1.0f / (float)ND);
}

// Round 5
// 290.528 us; speedup vs baseline: 4.0106x; 4.0106x over previous
//
#include <hip/hip_runtime.h>

// VQ-VAE vector quantizer forward (fp32).
// inputs: (32,256,32,32) f32 -> flat rows N=32768 x D=256
// embedding: (D=256, K=1024) f32, cluster_size: (1024,) f32
// outputs (flat f32): quantized[N*D], vq_loss, perplexity, code_usage, indices[N] (as float)

constexpr int DIM = 256;   // embedding dim (rows of embedding)
constexpr int NK  = 1024;  // number of codes (cols of embedding)
constexpr int RR  = 16;    // input rows per block in argmin kernel
constexpr int NG  = DIM / 4;  // 64 four-row groups (R4 bug: was 16 -> only 1/4 of dot product)

// async 16B global->LDS (no VGPR round-trip). HW dest = wave-uniform base +
// lane*16; our per-lane LDS pointers are exactly base + lane*16 (thread t
// <-> columns 4t..4t+3), so the staged layout matches.
#define GLL16(GSRC, LDST)                                                      \
  __builtin_amdgcn_global_load_lds(                                            \
      (const __attribute__((address_space(1))) void*)(GSRC),                   \
      (__attribute__((address_space(3))) void*)(LDST), 16, 0, 0)

// ---------------------------------------------------------------- enorm (0.5*|e_k|^2)
__global__ __launch_bounds__(256) void enorm_kernel(
    const float* __restrict__ emb, float* __restrict__ enorm) {
  int k = blockIdx.x * 256 + threadIdx.x;
  float s = 0.f;
  for (int d = 0; d < DIM; ++d) {
    float e = emb[(size_t)d * NK + k];   // coalesced across threads per d
    s = fmaf(e, e, s);
  }
  enorm[k] = 0.5f * s;                   // argmin(|e|^2-2x.e) == argmin(0.5|e|^2-x.e)
}

// ---------------------------------------------------------------- argmin
// Block: 256 threads, RR=16 input rows vs all 1024 codes.
// Thread t owns codes 4t..4t+3. Embedding rows staged 4-at-a-time into a
// double-buffered LDS tile via global_load_lds; each wave reads back ONLY the
// bytes its own lanes staged, so the main loop needs NO barriers — per-wave
// counted vmcnt keeps the next group's 4 loads in flight.
__global__ __launch_bounds__(256, 3) void argmin_kernel(
    const float* __restrict__ x, const float* __restrict__ emb,
    const float* __restrict__ enorm, int* __restrict__ idx_out,
    float* __restrict__ idx_out_f) {
  __shared__ float xs[RR * DIM];    // 16 KB x-tile (cross-wave broadcast reads)
  __shared__ float es[2][4][NK];    // 32 KB double-buffered e-tile (4 rows each)
  __shared__ float red_v[4][RR];
  __shared__ int   red_i[4][RR];

  const int tid = threadIdx.x;
  const int k0  = tid * 4;
  const size_t xbase = (size_t)blockIdx.x * (RR * DIM);

  // Stage x-tile (lane-linear: dest = base + lane*16) and e-group 0.
  #pragma unroll
  for (int i = 0; i < 4; ++i)
    GLL16(x + xbase + (size_t)(tid + 256 * i) * 4, &xs[(tid + 256 * i) * 4]);
  #pragma unroll
  for (int r = 0; r < 4; ++r)
    GLL16(emb + (size_t)r * NK + k0, &es[0][r][k0]);
  __syncthreads();   // drains vmcnt(0): x-tile + group 0 resident

  float acc[RR][4];
  #pragma unroll
  for (int r = 0; r < RR; ++r) {
    #pragma unroll
    for (int j = 0; j < 4; ++j) acc[r][j] = 0.f;
  }

  #pragma unroll 2
  for (int g = 0; g < NG; ++g) {
    if (g < NG - 1) {
      // issue next 4-row group into the other buffer (stays in flight)
      const float* src = emb + (size_t)((g + 1) * 4) * NK + k0;
      #pragma unroll
      for (int r = 0; r < 4; ++r)
        GLL16(src + (size_t)r * NK, &es[(g + 1) & 1][r][k0]);
      asm volatile("s_waitcnt vmcnt(4)" ::: "memory");  // group g landed; g+1 in flight
    } else {
      asm volatile("s_waitcnt vmcnt(0)" ::: "memory");
    }
    __builtin_amdgcn_sched_barrier(0);

    const int b = g & 1;
    const float4 e0 = *(const float4*)&es[b][0][k0];
    const float4 e1 = *(const float4*)&es[b][1][k0];
    const float4 e2 = *(const float4*)&es[b][2][k0];
    const float4 e3 = *(const float4*)&es[b][3][k0];
    #pragma unroll
    for (int r = 0; r < RR; ++r) {
      const float4 xv = *(const float4*)&xs[r * DIM + g * 4];   // LDS broadcast
      acc[r][0] = fmaf(xv.x, e0.x, fmaf(xv.y, e1.x, fmaf(xv.z, e2.x, fmaf(xv.w, e3.x, acc[r][0]))));
      acc[r][1] = fmaf(xv.x, e0.y, fmaf(xv.y, e1.y, fmaf(xv.z, e2.y, fmaf(xv.w, e3.y, acc[r][1]))));
      acc[r][2] = fmaf(xv.x, e0.z, fmaf(xv.y, e1.z, fmaf(xv.z, e2.z, fmaf(xv.w, e3.z, acc[r][2]))));
      acc[r][3] = fmaf(xv.x, e0.w, fmaf(xv.y, e1.w, fmaf(xv.z, e2.w, fmaf(xv.w, e3.w, acc[r][3]))));
    }
  }

  const float4 en = *(const float4*)(enorm + k0);   // 0.5*|e|^2
  const int lane = tid & 63;
  const int wv   = tid >> 6;

  for (int r = 0; r < RR; ++r) {
    // score = 0.5|e|^2 - x.e  (row-constant |x|^2 and global 2x dropped)
    float bv = en.x - acc[r][0];
    int   bi = k0;
    { float v = en.y - acc[r][1]; if (v < bv) { bv = v; bi = k0 + 1; } }
    { float v = en.z - acc[r][2]; if (v < bv) { bv = v; bi = k0 + 2; } }
    { float v = en.w - acc[r][3]; if (v < bv) { bv = v; bi = k0 + 3; } }
    // 64-lane (val,idx) min-reduce, lowest index wins ties
    for (int off = 32; off > 0; off >>= 1) {
      float ov = __shfl_xor(bv, off);
      int   oi = __shfl_xor(bi, off);
      if (ov < bv || (ov == bv && oi < bi)) { bv = ov; bi = oi; }
    }
    if (lane == 0) { red_v[wv][r] = bv; red_i[wv][r] = bi; }
  }
  __syncthreads();

  if (tid < RR) {
    float bv = red_v[0][tid];
    int   bi = red_i[0][tid];
    #pragma unroll
    for (int w = 1; w < 4; ++w) {
      float v = red_v[w][tid]; int i2 = red_i[w][tid];
      if (v < bv || (v == bv && i2 < bi)) { bv = v; bi = i2; }
    }
    const int n = blockIdx.x * RR + tid;
    idx_out[n]   = bi;
    idx_out_f[n] = (float)bi;
  }
}

// ---------------------------------------------------------------- gather + loss partials
// Block: 256 threads x 8 elems = 2048 elems (8 rows).
__global__ __launch_bounds__(256) void gather_loss_kernel(
    const float* __restrict__ x, const float* __restrict__ emb,
    const int* __restrict__ idx, float* __restrict__ out_q,
    float* __restrict__ partial) {
  const int tid = threadIdx.x;
  const size_t base = (size_t)blockIdx.x * 2048;
  float local = 0.f;
  #pragma unroll
  for (int h = 0; h < 2; ++h) {
    const size_t g = base + (size_t)h * 1024 + (size_t)tid * 4;
    const int n = (int)(g >> 8);
    const int d = (int)(g & 255);
    const int k = idx[n];
    const float* ep = emb + (size_t)d * NK + k;
    float4 q;
    q.x = ep[0]; q.y = ep[NK]; q.z = ep[2 * NK]; q.w = ep[3 * NK];
    const float4 xv = *(const float4*)(x + g);
    *(float4*)(out_q + g) = q;
    const float dx = q.x - xv.x, dy = q.y - xv.y, dz = q.z - xv.z, dw = q.w - xv.w;
    local = fmaf(dx, dx, local);
    local = fmaf(dy, dy, local);
    local = fmaf(dz, dz, local);
    local = fmaf(dw, dw, local);
  }
  for (int off = 32; off > 0; off >>= 1) local += __shfl_down(local, off);
  __shared__ float wsum[4];
  if ((tid & 63) == 0) wsum[tid >> 6] = local;
  __syncthreads();
  if (tid == 0) partial[blockIdx.x] = (wsum[0] + wsum[1]) + (wsum[2] + wsum[3]);
}

// ---------------------------------------------------------------- finalize scalars
__global__ __launch_bounds__(1024) void finalize_kernel(
    const float* __restrict__ partial, int np,
    const float* __restrict__ cs, float* __restrict__ out_s,
    float inv_count) {
  __shared__ float sd[1024];
  const int tid = threadIdx.x;

  // 1) total squared diff
  float s = 0.f;
  for (int i = tid; i < np; i += 1024) s += partial[i];
  sd[tid] = s; __syncthreads();
  for (int st = 512; st > 0; st >>= 1) {
    if (tid < st) sd[tid] += sd[tid + st];
    __syncthreads();
  }
  const float total_sq = sd[0];
  __syncthreads();

  // 2) cluster_size sum
  const float c = cs[tid];
  sd[tid] = c; __syncthreads();
  for (int st = 512; st > 0; st >>= 1) {
    if (tid < st) sd[tid] += sd[tid + st];
    __syncthreads();
  }
  const float S = sd[0];
  __syncthreads();

  // 3) entropy term
  const float p = c / (S + 1e-5f);
  sd[tid] = p * logf(p + 1e-5f);
  __syncthreads();
  for (int st = 512; st > 0; st >>= 1) {
    if (tid < st) sd[tid] += sd[tid + st];
    __syncthreads();
  }
  const float T = sd[0];
  __syncthreads();

  // 4) used codes
  sd[tid] = (c > 1e-5f) ? 1.f : 0.f;
  __syncthreads();
  for (int st = 512; st > 0; st >>= 1) {
    if (tid < st) sd[tid] += sd[tid + st];
    __syncthreads();
  }
  const float U = sd[0];

  if (tid == 0) {
    out_s[0] = 1.25f * total_sq * inv_count;  // e_latent + 0.25*q_latent (equal in value)
    out_s[1] = expf(-T);                      // perplexity
    out_s[2] = U * (1.f / 1024.f);            // code usage rate
  }
}

// ---------------------------------------------------------------- launch
extern "C" void kernel_launch(void* const* d_in, const int* in_sizes, int n_in,
                              void* d_out, int out_size, void* d_ws, size_t ws_size,
                              hipStream_t stream) {
  const float* x   = (const float*)d_in[0];
  const float* emb = (const float*)d_in[1];
  const float* cs  = (const float*)d_in[2];
  float* out = (float*)d_out;

  const int N = in_sizes[0] / DIM;          // 32768
  const size_t ND = (size_t)N * DIM;        // 8388608

  // workspace layout
  float* enorm   = (float*)d_ws;                                           // 4 KB
  int*   idxw    = (int*)((char*)d_ws + NK * sizeof(float));               // 128 KB
  float* partial = (float*)((char*)d_ws + NK * sizeof(float) + (size_t)N * sizeof(int)); // 16 KB

  const int nGather = (int)(ND / 2048);     // 4096

  enorm_kernel<<<NK / 256, 256, 0, stream>>>(emb, enorm);
  argmin_kernel<<<N / RR, 256, 0, stream>>>(x, emb, enorm, idxw, out + ND + 3);
  gather_loss_kernel<<<nGather, 256, 0, stream>>>(x, emb, idxw, out, partial);
  finalize_kernel<<<1, 1024, 0, stream>>>(partial, nGather, cs, out + ND,
                                          1.0f / (float)ND);
}